// Round 5
// baseline (191.935 us; speedup 1.0000x reference)
//
#include <hip/hip_runtime.h>
#include <math.h>

#define N_TOK 32768
#define DIM   512
#define NEXP  16
#define CAP   2457
#define CAPP  2464
#define NCHUNK 1024  // chunks of 32 tokens

typedef __attribute__((ext_vector_type(8))) short   short8;
typedef __attribute__((ext_vector_type(4))) short   short4v;
typedef __attribute__((ext_vector_type(4))) float   floatx4;

__device__ __forceinline__ short f2bf(float f) {
  unsigned u = __builtin_bit_cast(unsigned, f);
  unsigned r = u + 0x7FFFu + ((u >> 16) & 1u);   // round-to-nearest-even bf16
  return (short)(r >> 16);
}
__device__ __forceinline__ float bf2f(short h) {
  return __builtin_bit_cast(float, ((unsigned)(unsigned short)h) << 16);
}

// ---------------- K1: MFMA router, K-split across wave pairs ----------------
// 1024 blocks x 256 threads; block = 32 tokens. Wave (pair,half): 16x16x32
// MFMA over K-half [half*256, half*256+256); partials summed via LDS.
#define LGP 17
__global__ __launch_bounds__(256) void router_k(
    const float* __restrict__ x, const float* __restrict__ sw,
    const float* __restrict__ sb, const float* __restrict__ ew,
    int* __restrict__ route, float* __restrict__ prob, int* __restrict__ hist,
    short* __restrict__ x_bf, short* __restrict__ w_bf) {
  __shared__ short swh[16][520];
  __shared__ short swl[16][520];
  __shared__ float lgt[4][16][LGP];
  __shared__ float sbs[NEXP];

  int tid = threadIdx.x;

  // folded convw: 1024 float4 of expert_w per block (4/thread)
  {
    const float4* src = (const float4*)ew;
    short4v* dst = (short4v*)w_bf;
    int base = blockIdx.x * 1024 + tid;
#pragma unroll
    for (int i = 0; i < 4; ++i) {
      float4 f = src[base + i * 256];
      short4v s;
      s[0] = f2bf(f.x); s[1] = f2bf(f.y); s[2] = f2bf(f.z); s[3] = f2bf(f.w);
      dst[base + i * 256] = s;
    }
  }

  // stage sw hi/lo into LDS (2048 float4, 8/thread)
  {
    int idx = tid;
#pragma unroll
    for (int i = 0; i < 8; ++i, idx += 256) {
      int e = idx >> 7, k4 = idx & 127;
      float4 f = ((const float4*)(sw + e * DIM))[k4];
      short4v h, l;
      h[0] = f2bf(f.x); h[1] = f2bf(f.y); h[2] = f2bf(f.z); h[3] = f2bf(f.w);
      l[0] = f2bf(f.x - bf2f(h[0]));
      l[1] = f2bf(f.y - bf2f(h[1]));
      l[2] = f2bf(f.z - bf2f(h[2]));
      l[3] = f2bf(f.w - bf2f(h[3]));
      *(short4v*)&swh[e][k4 * 4] = h;
      *(short4v*)&swl[e][k4 * 4] = l;
    }
  }
  if (tid < NEXP) sbs[tid] = sb[tid];
  __syncthreads();

  int wv = tid >> 6, lane = tid & 63, q = lane >> 4, l16 = lane & 15;
  int pair = wv >> 1, half = wv & 1;
  int row = blockIdx.x * 32 + pair * 16 + l16;
  const float* xr = x + (size_t)row * DIM;
  short* xbr = x_bf + (size_t)row * DIM;

  floatx4 acc = {};
#pragma unroll
  for (int i = 0; i < 8; ++i) {
    int k0 = (half * 8 + i) * 32 + q * 8;
    float4 f0 = *(const float4*)(xr + k0);
    float4 f1 = *(const float4*)(xr + k0 + 4);
    short8 hi, lo;
    hi[0] = f2bf(f0.x); hi[1] = f2bf(f0.y); hi[2] = f2bf(f0.z); hi[3] = f2bf(f0.w);
    hi[4] = f2bf(f1.x); hi[5] = f2bf(f1.y); hi[6] = f2bf(f1.z); hi[7] = f2bf(f1.w);
    lo[0] = f2bf(f0.x - bf2f(hi[0])); lo[1] = f2bf(f0.y - bf2f(hi[1]));
    lo[2] = f2bf(f0.z - bf2f(hi[2])); lo[3] = f2bf(f0.w - bf2f(hi[3]));
    lo[4] = f2bf(f1.x - bf2f(hi[4])); lo[5] = f2bf(f1.y - bf2f(hi[5]));
    lo[6] = f2bf(f1.z - bf2f(hi[6])); lo[7] = f2bf(f1.w - bf2f(hi[7]));
    *(short8*)(xbr + k0) = hi;
    short8 bh = *(const short8*)&swh[l16][k0];
    short8 bl = *(const short8*)&swl[l16][k0];
    acc = __builtin_amdgcn_mfma_f32_16x16x32_bf16(hi, bh, acc, 0, 0, 0);
    acc = __builtin_amdgcn_mfma_f32_16x16x32_bf16(lo, bh, acc, 0, 0, 0);
    acc = __builtin_amdgcn_mfma_f32_16x16x32_bf16(hi, bl, acc, 0, 0, 0);
    acc = __builtin_amdgcn_mfma_f32_16x16x32_bf16(lo, bl, acc, 0, 0, 0);
  }
#pragma unroll
  for (int r = 0; r < 4; ++r)
    lgt[wv][q * 4 + r][l16] = acc[r];
  __syncthreads();

  if (tid < 32) {
    int t = blockIdx.x * 32 + tid;
    int p = tid >> 4, tk = tid & 15;
    float lg[NEXP];
#pragma unroll
    for (int e = 0; e < NEXP; ++e)
      lg[e] = lgt[p * 2][tk][e] + lgt[p * 2 + 1][tk][e] + sbs[e];
    int arg = 0; float mx = lg[0];
#pragma unroll
    for (int e = 1; e < NEXP; ++e)
      if (lg[e] > mx) { mx = lg[e]; arg = e; }
    float s = 0.f;
#pragma unroll
    for (int e = 0; e < NEXP; ++e) s += expf(lg[e] - mx);
    route[t] = arg;
    prob[t]  = 1.0f / s;
#pragma unroll
    for (int e = 0; e < NEXP; ++e) {
      unsigned long long m = __ballot(arg == e);
      if (tid == e) hist[blockIdx.x * NEXP + e] = __popcll(m);
    }
  }
}

// ---------------- K2: positions + fused chunk-prefix scan -------------------
// 128 blocks x 256 threads; block b = tokens [b*256,(b+1)*256) = chunks 8b..8b+7
__global__ __launch_bounds__(256) void pos_k(
    const int* __restrict__ route, const float* __restrict__ prob,
    const int* __restrict__ hist, const float* __restrict__ x,
    float* __restrict__ out, int* __restrict__ lists,
    int* __restrict__ counts) {
  __shared__ int part[16][NEXP];
  __shared__ int base_s[NEXP];
  __shared__ int wcnt[4][NEXP];
  int tid = threadIdx.x;
  int b = blockIdx.x;
  int c0 = b * 8;
  {
    int g = tid >> 4, e = tid & 15;
    int s = 0;
    for (int c = g; c < c0; c += 16) s += hist[c * NEXP + e];
    part[g][e] = s;
  }
  __syncthreads();
  if (tid < NEXP) {
    int s = 0;
#pragma unroll
    for (int gg = 0; gg < 16; ++gg) s += part[gg][tid];
    base_s[tid] = s;
  }
  int wv = tid >> 6, lane = tid & 63;
  int t = b * 256 + wv * 64 + lane;
  int r = route[t];
  unsigned long long lower = (1ull << lane) - 1ull;
  int rank = 0;
#pragma unroll
  for (int e = 0; e < NEXP; ++e) {
    unsigned long long m = __ballot(r == e);
    if (r == e) rank = __popcll(m & lower);
    if (lane == e) wcnt[wv][e] = __popcll(m);
  }
  __syncthreads();
  int pre = base_s[r];
  for (int w2 = 0; w2 < wv; ++w2) pre += wcnt[w2][r];
  int pos = pre + rank;
  if (pos < CAP) {
    lists[r * CAPP + pos] = t;
  } else {
    float p = prob[t];
    const float4* xr = (const float4*)(x + (size_t)t * DIM);
    float4* o = (float4*)(out + (size_t)t * DIM);
    for (int d = 0; d < DIM / 4; ++d) {
      float4 v = xr[d];
      v.x *= p; v.y *= p; v.z *= p; v.w *= p;
      o[d] = v;
    }
  }
  if (b == 127 && tid < NEXP)
    counts[tid] = base_s[tid] + wcnt[0][tid] + wcnt[1][tid]
                + wcnt[2][tid] + wcnt[3][tid];
}

// ---------------- K3: grouped GEMM, 64x256 tile -----------------------------
// Wave wv owns all 64 rows x cols [wv*64, wv*64+64): acc 4x4, 256 MFMA/wave.
#define BM 64
#define BN 256
#define BKS 64

__global__ __launch_bounds__(256, 4) void gemm_k(
    const short* __restrict__ x_bf, const short* __restrict__ w_bf,
    const float* __restrict__ eb, const int* __restrict__ lists,
    const int* __restrict__ counts, const float* __restrict__ prob,
    float* __restrict__ out) {
  int e = blockIdx.z;
  int cnt = counts[e]; if (cnt > CAP) cnt = CAP;
  int row0 = blockIdx.y * BM;
  if (row0 >= cnt) return;
  int col0 = blockIdx.x * BN;

  __shared__ short A_s[BM * BKS];   // 8 KB
  __shared__ short B_s[BN * BKS];   // 32 KB
  __shared__ int rowtok[BM];

  int tid = threadIdx.x;
  if (tid < BM) {
    int gr = row0 + tid;
    rowtok[tid] = (gr < cnt) ? lists[e * CAPP + gr] : 0;
  }
  __syncthreads();

  int wv = tid >> 6, lane = tid & 63;
  int q = lane >> 4, l16 = lane & 15;
  int r_loc = lane >> 3, c = lane & 7;

  // A staging: wave wv stages rows [wv*16, wv*16+16) (2 instrs)
  const short* ga[2]; short* la[2];
#pragma unroll
  for (int t2 = 0; t2 < 2; ++t2) {
    int row = wv * 16 + t2 * 8 + r_loc;
    int g = c ^ (row & 7);
    ga[t2] = x_bf + (size_t)rowtok[row] * DIM + g * 8;
    la[t2] = &A_s[(wv * 16 + t2 * 8) * BKS];    // wave-uniform base
  }
  // B staging: wave wv stages rows [wv*64, wv*64+64) (8 instrs)
  const short* gb[8]; short* lb[8];
#pragma unroll
  for (int t8 = 0; t8 < 8; ++t8) {
    int row = wv * 64 + t8 * 8 + r_loc;
    int g = c ^ (row & 7);
    gb[t8] = w_bf + (size_t)(e * DIM + col0 + row) * DIM + g * 8;
    lb[t8] = &B_s[(wv * 64 + t8 * 8) * BKS];
  }

  floatx4 acc[4][4] = {};

  for (int k0 = 0; k0 < DIM; k0 += BKS) {
#pragma unroll
    for (int t2 = 0; t2 < 2; ++t2)
      __builtin_amdgcn_global_load_lds(
          (const __attribute__((address_space(1))) void*)(ga[t2] + k0),
          (__attribute__((address_space(3))) void*)(la[t2]), 16, 0, 0);
#pragma unroll
    for (int t8 = 0; t8 < 8; ++t8)
      __builtin_amdgcn_global_load_lds(
          (const __attribute__((address_space(1))) void*)(gb[t8] + k0),
          (__attribute__((address_space(3))) void*)(lb[t8]), 16, 0, 0);
    __syncthreads();
#pragma unroll
    for (int kk = 0; kk < 2; ++kk) {
      short8 af[4], bfv[4];
      int ckbase = kk * 4 + q;
#pragma unroll
      for (int sm = 0; sm < 4; ++sm) {
        int row = sm * 16 + l16;
        int ph = ckbase ^ (row & 7);
        af[sm] = *(const short8*)&A_s[row * BKS + ph * 8];
      }
#pragma unroll
      for (int sn = 0; sn < 4; ++sn) {
        int row = wv * 64 + sn * 16 + l16;
        int ph = ckbase ^ (row & 7);
        bfv[sn] = *(const short8*)&B_s[row * BKS + ph * 8];
      }
#pragma unroll
      for (int sm = 0; sm < 4; ++sm)
#pragma unroll
        for (int sn = 0; sn < 4; ++sn)
          acc[sm][sn] = __builtin_amdgcn_mfma_f32_16x16x32_bf16(
              af[sm], bfv[sn], acc[sm][sn], 0, 0, 0);
    }
    __syncthreads();
  }

#pragma unroll
  for (int sm = 0; sm < 4; ++sm) {
    int tt[4]; float pp[4]; int vld[4];
#pragma unroll
    for (int rg = 0; rg < 4; ++rg) {
      int rr = sm * 16 + q * 4 + rg;
      int gr = row0 + rr;
      vld[rg] = (gr < cnt);
      tt[rg]  = rowtok[rr];
      pp[rg]  = vld[rg] ? prob[tt[rg]] : 0.f;
    }
#pragma unroll
    for (int sn = 0; sn < 4; ++sn) {
      int col = col0 + wv * 64 + sn * 16 + l16;
      float bias = eb[e * DIM + col];
#pragma unroll
      for (int rg = 0; rg < 4; ++rg)
        if (vld[rg])
          out[(size_t)tt[rg] * DIM + col] = (acc[sm][sn][rg] + bias) * pp[rg];
    }
  }
}

extern "C" void kernel_launch(void* const* d_in, const int* in_sizes, int n_in,
                              void* d_out, int out_size, void* d_ws, size_t ws_size,
                              hipStream_t stream) {
  const float* x  = (const float*)d_in[0];
  const float* sw = (const float*)d_in[1];
  const float* sb = (const float*)d_in[2];
  const float* ew = (const float*)d_in[3];
  const float* eb = (const float*)d_in[4];
  float* out = (float*)d_out;

  char* ws = (char*)d_ws;
  int*   route  = (int*)(ws + 0);          // 32768*4
  float* prob   = (float*)(ws + 131072);   // 32768*4
  int*   hist   = (int*)(ws + 262144);     // 1024*16*4 = 64KB
  int*   counts = (int*)(ws + 327680);     // 16*4
  int*   lists  = (int*)(ws + 327744);     // 16*2464*4
  short* x_bf   = (short*)(ws + (1 << 20));
  short* w_bf   = (short*)(ws + (1 << 20) + 33554432);

  hipLaunchKernelGGL(router_k, dim3(NCHUNK), dim3(256), 0, stream,
                     x, sw, sb, ew, route, prob, hist, x_bf, w_bf);
  hipLaunchKernelGGL(pos_k, dim3(128), dim3(256), 0, stream,
                     route, prob, hist, x, out, lists, counts);
  hipLaunchKernelGGL(gemm_k, dim3(2, 39, 16), dim3(256), 0, stream,
                     x_bf, w_bf, eb, lists, counts, prob, out);
}